// Round 4
// baseline (427.228 us; speedup 1.0000x reference)
//
#include <hip/hip_runtime.h>
#include <float.h>
#include <math.h>

// NormEMAVectorQuantizer via split-bf16 MFMA + exact fp32 refinement.
// z (8,2048,256) f32, weight (8192,256) f32 (unit rows).
// out = [ z_q (16384*256) | loss (1) | indices (16384, as float) ]
//
// Round-4: k_coarse rebuilt as 256x256 tile, BK=32, 8 waves (2x4, 128x64
// each -> 0.375 ds_reads/MFMA), TRIPLE-buffered LDS (96 KB) so staging
// tile t+2 during tile t is WAR-free by construction; constant counted
// s_waitcnt vmcnt(4) at tile boundaries (never drains to 0 mid-loop).

#define BT_ 16384
#define D_  256
#define N_  8192
#define BETA_ 1.0f
#define THR_ 5e-4f

#define BM 256
#define BN 256
#define NKT 24           // 768 / 32 K-tiles
#define NTILES 32        // N_ / BN

typedef __attribute__((ext_vector_type(8))) short bf16x8;
typedef __attribute__((ext_vector_type(4))) float f32x4;

__device__ __forceinline__ void gld16(void* lds, const void* g) {
  __builtin_amdgcn_global_load_lds(
      (const __attribute__((address_space(1))) void*)g,
      (__attribute__((address_space(3))) void*)lds, 16, 0, 0);
}

__device__ __forceinline__ unsigned short f2bf(float x) {
  unsigned u = __float_as_uint(x);
  u += 0x7FFFu + ((u >> 16) & 1u);
  return (unsigned short)(u >> 16);
}
__device__ __forceinline__ float bf2f(unsigned short h) {
  return __uint_as_float(((unsigned)h) << 16);
}

// ---------------- kernel 1: normalize z, store zn + split A_cat ----------------
__global__ __launch_bounds__(256) void k_prep_z(const float* __restrict__ z,
                                                float* __restrict__ zn,
                                                ushort* __restrict__ Acat) {
  const int row  = blockIdx.x * 4 + (threadIdx.x >> 6);
  const int lane = threadIdx.x & 63;
  float4 v = *(reinterpret_cast<const float4*>(z) + (size_t)row * 64 + lane);
  float s = v.x * v.x + v.y * v.y + v.z * v.z + v.w * v.w;
#pragma unroll
  for (int o = 32; o > 0; o >>= 1) s += __shfl_xor(s, o, 64);
  float dn = fmaxf(sqrtf(s), 1e-12f);
  v.x /= dn; v.y /= dn; v.z /= dn; v.w /= dn;
  *(reinterpret_cast<float4*>(zn) + (size_t)row * 64 + lane) = v;
  ushort4 h  = make_ushort4(f2bf(v.x), f2bf(v.y), f2bf(v.z), f2bf(v.w));
  ushort4 lo = make_ushort4(f2bf(v.x - bf2f(h.x)), f2bf(v.y - bf2f(h.y)),
                            f2bf(v.z - bf2f(h.z)), f2bf(v.w - bf2f(h.w)));
  ushort4* A4 = reinterpret_cast<ushort4*>(Acat);
  size_t rb = (size_t)row * 192 + lane;   // 768/4 = 192 ushort4 per row
  A4[rb]       = h;    // zh
  A4[rb + 64]  = h;    // zh
  A4[rb + 128] = lo;   // zl
}

// ---------------- kernel 2: wn2, split B_cat ----------------
__global__ __launch_bounds__(256) void k_prep_w(const float* __restrict__ w,
                                                float* __restrict__ wn2,
                                                ushort* __restrict__ Bcat) {
  const int row  = blockIdx.x * 4 + (threadIdx.x >> 6);
  const int lane = threadIdx.x & 63;
  float4 v = *(reinterpret_cast<const float4*>(w) + (size_t)row * 64 + lane);
  float s = v.x * v.x + v.y * v.y + v.z * v.z + v.w * v.w;
#pragma unroll
  for (int o = 32; o > 0; o >>= 1) s += __shfl_xor(s, o, 64);
  if (lane == 0) wn2[row] = s;
  ushort4 h  = make_ushort4(f2bf(v.x), f2bf(v.y), f2bf(v.z), f2bf(v.w));
  ushort4 lo = make_ushort4(f2bf(v.x - bf2f(h.x)), f2bf(v.y - bf2f(h.y)),
                            f2bf(v.z - bf2f(h.z)), f2bf(v.w - bf2f(h.w)));
  ushort4* B4 = reinterpret_cast<ushort4*>(Bcat);
  size_t rb = (size_t)row * 192 + lane;
  B4[rb]       = h;    // wh
  B4[rb + 64]  = lo;   // wl
  B4[rb + 128] = h;    // wh
}

// ---------------- kernel 3: MFMA GEMM, 256x256, BK=32, triple buffer --------
// grid = 64 rt x 32 ct = 2048 blocks, 512 threads (8 waves, 2M x 4N).
// Per wave per K-tile: 12 ds_read_b128, 32 MFMA, 4 gld16 (stage t+2).
// LDS swizzle (64B rows, 4x16B slots): LDS[r][s] = global[r][s ^ (r&3)].
__global__ __launch_bounds__(512, 2) void k_coarse(const ushort* __restrict__ Acat,
                                                   const ushort* __restrict__ Bcat,
                                                   const float* __restrict__ wn2,
                                                   float* __restrict__ tm,
                                                   float* __restrict__ ts,
                                                   int* __restrict__ ti) {
  extern __shared__ char smem[];
  char* ldsA = smem;             // 3 x 16384
  char* ldsB = smem + 49152;     // 3 x 16384
  __shared__ float wn2s[256];
  __shared__ float red_m[256][4];
  __shared__ float red_s[256][4];
  __shared__ int   red_i[256][4];

  const int tid = threadIdx.x;
  const int l   = tid & 63;
  const int wv  = tid >> 6;
  const int wr  = wv >> 2;       // 0..1 -> rows wr*128
  const int wc  = wv & 3;        // 0..3 -> cols wc*64
  // XCD-aware 2D-chunked swizzle: per XCD, concurrent ~32 blocks cover a
  // 4rt x 8ct chunk (working set ~4.5 MB ~= L2).
  const int bid  = blockIdx.x;
  const int xcd  = bid & 7;
  const int q    = bid >> 3;              // 0..255 within XCD
  const int chnk = q >> 5, wq = q & 31;   // 8 chunks of 32
  const int rt   = xcd * 8 + (chnk >> 2) * 4 + (wq >> 3);
  const int ct   = (chnk & 3) * 8 + (wq & 7);
  const int row0 = rt * BM;
  const int col0 = ct * BN;

  if (tid < 256) wn2s[tid] = wn2[col0 + tid];

  // staging source (pre-swizzled): lane l covers row (l>>2) of a 16-row/1KB
  // chunk, slot (l&3); source slot = (l&3) ^ ((l>>2)&3).
  const int srow = l >> 2;
  const int sslt = ((l & 3) ^ (srow & 3)) * 16;
  const char* aSrc = (const char*)Acat + (size_t)(row0 + wv * 16 + srow) * 1536 + sslt;
  const char* bSrc = (const char*)Bcat + (size_t)(col0 + wv * 16 + srow) * 1536 + sslt;

  // fragment read offsets: row R = (base + l&15), byte = R*64 + ((l>>4)^(R&3))*16
  const int lA   = l & 15;
  const int aOff = (wr * 128 + lA) * 64 + (((l >> 4) ^ (lA & 3)) << 4);
  const int bOff = (wc * 64  + lA) * 64 + (((l >> 4) ^ (lA & 3)) << 4);

#define STAGE(t)                                                               \
  do {                                                                         \
    char* _a = ldsA + ((t) % 3) * 16384 + (wv << 10);                          \
    char* _b = ldsB + ((t) % 3) * 16384 + (wv << 10);                          \
    const char* _sa = aSrc + (size_t)(t) * 64;                                 \
    const char* _sb = bSrc + (size_t)(t) * 64;                                 \
    gld16(_a, _sa);           gld16(_a + 8192, _sa + (size_t)128 * 1536);      \
    gld16(_b, _sb);           gld16(_b + 8192, _sb + (size_t)128 * 1536);      \
  } while (0)

  f32x4 acc[8][4];
#pragma unroll
  for (int i = 0; i < 8; ++i)
#pragma unroll
    for (int j = 0; j < 4; ++j) acc[i][j] = (f32x4){0.f, 0.f, 0.f, 0.f};

  // prologue: stage tiles 0 and 1 (4 loads each per wave)
  STAGE(0);
  STAGE(1);

  for (int t = 0; t < NKT; ++t) {
    const int bo = (t % 3) * 16384;
    // tile t's 4 loads are older than tile t+1's 4 still allowed in flight.
    asm volatile("s_waitcnt vmcnt(4)" ::: "memory");
    __builtin_amdgcn_s_barrier();
    __builtin_amdgcn_sched_barrier(0);
    if (t + 2 < NKT) STAGE(t + 2);   // buf (t+2)%3 == tile t-1's (reads done)
    bf16x8 af[8], bg[4];
#pragma unroll
    for (int m = 0; m < 8; ++m)
      af[m] = *(const bf16x8*)(ldsA + bo + aOff + m * 1024);
#pragma unroll
    for (int n = 0; n < 4; ++n)
      bg[n] = *(const bf16x8*)(ldsB + bo + bOff + n * 1024);
    __builtin_amdgcn_s_setprio(1);
#pragma unroll
    for (int m = 0; m < 8; ++m)
#pragma unroll
      for (int n = 0; n < 4; ++n)
        acc[m][n] = __builtin_amdgcn_mfma_f32_16x16x32_bf16(af[m], bg[n], acc[m][n], 0, 0, 0);
    __builtin_amdgcn_s_setprio(0);
  }
#undef STAGE

  // epilogue: distances + per-row (m, s, idx) over this 256-code tile.
  // C layout (16x16x32): col = lane&15, row = (lane>>4)*4 + reg
#pragma unroll
  for (int i = 0; i < 8; ++i) {
#pragma unroll
    for (int qq = 0; qq < 4; ++qq) {
      float m = FLT_MAX, s = FLT_MAX; int bi = 0;
#pragma unroll
      for (int j = 0; j < 4; ++j) {
        int cl = wc * 64 + j * 16 + lA;
        float d = fmaf(-2.0f, acc[i][j][qq], wn2s[cl]);
        int c = col0 + cl;
        if (d < m) { s = m; m = d; bi = c; }
        else if (d < s) { s = d; }
      }
#pragma unroll
      for (int msk = 1; msk < 16; msk <<= 1) {
        float om = __shfl_xor(m, msk, 64);
        float os = __shfl_xor(s, msk, 64);
        int   oi = __shfl_xor(bi, msk, 64);
        float nsv = fminf(fminf(s, os), fmaxf(m, om));
        if (om < m || (om == m && oi < bi)) { m = om; bi = oi; }
        s = nsv;
      }
      if (lA == 0) {
        int rl = wr * 128 + i * 16 + (l >> 4) * 4 + qq;
        red_m[rl][wc] = m; red_s[rl][wc] = s; red_i[rl][wc] = bi;
      }
    }
  }
  __syncthreads();
  if (tid < BM) {
    float m = red_m[tid][0], s = red_s[tid][0]; int bi = red_i[tid][0];
#pragma unroll
    for (int k = 1; k < 4; ++k) {
      float om = red_m[tid][k], os = red_s[tid][k]; int oi = red_i[tid][k];
      float nsv = fminf(fminf(s, os), fmaxf(m, om));
      if (om < m || (om == m && oi < bi)) { m = om; bi = oi; }
      s = nsv;
    }
    size_t o = (size_t)ct * BT_ + row0 + tid;
    tm[o] = m; ts[o] = s; ti[o] = bi;
  }
}

// ---------------- kernel 4: combine tiles per row, flag ambiguous ----------------
__global__ __launch_bounds__(256) void k_combine(const float* __restrict__ tm,
                                                 const float* __restrict__ ts,
                                                 const int* __restrict__ ti,
                                                 int* __restrict__ idxf,
                                                 int* __restrict__ flagged,
                                                 int* __restrict__ count) {
  const int row = blockIdx.x * 256 + threadIdx.x;
  float m = FLT_MAX, s = FLT_MAX; int bi = 0x7fffffff;
  for (int t = 0; t < NTILES; ++t) {
    size_t o = (size_t)t * BT_ + row;
    float om = tm[o], os = ts[o]; int oi = ti[o];
    float nsv = fminf(fminf(s, os), fmaxf(m, om));
    if (om < m || (om == m && oi < bi)) { m = om; bi = oi; }
    s = nsv;
  }
  idxf[row] = bi;
  if (s - m <= THR_) {
    int p = atomicAdd(count, 1);
    flagged[p] = row;
  }
}

// ---------------- kernel 5: exact fp32 refinement of flagged rows ----------------
// 2048 blocks x 128 threads; one flagged row per block (grid-stride).
__global__ __launch_bounds__(128) void k_refine(const float* __restrict__ zn,
                                                const float* __restrict__ w,
                                                const float* __restrict__ wn2,
                                                const float* __restrict__ tm,
                                                const int* __restrict__ flagged,
                                                const int* __restrict__ count,
                                                int* __restrict__ idxf) {
  __shared__ float4 znr[64];
  __shared__ float tmr[32];
  __shared__ float m1s;
  __shared__ float wd[2];
  __shared__ int   wi[2];
  const int tid = threadIdx.x;
  const int cnt = *count;
  for (int f = blockIdx.x; f < cnt; f += gridDim.x) {
    __syncthreads();   // protect LDS reuse across iterations
    const int row = flagged[f];
    if (tid < 64) {
      znr[tid] = *(reinterpret_cast<const float4*>(zn) + (size_t)row * 64 + tid);
    }
    if (tid < 32) {
      float tv = tm[(size_t)tid * BT_ + row];
      tmr[tid] = tv;
      float mm = tv;
#pragma unroll
      for (int msk = 16; msk > 0; msk >>= 1) mm = fminf(mm, __shfl_xor(mm, msk, 64));
      if (tid == 0) m1s = mm;
    }
    __syncthreads();
    const float lim = m1s + THR_;
    float bd = FLT_MAX; int bi = 0x7fffffff;
    for (int t = 0; t < NTILES; ++t) {
      if (tmr[t] <= lim) {
#pragma unroll
        for (int h = 0; h < 2; ++h) {
          int c = t * BN + h * 128 + tid;
          const float4* wr4 = reinterpret_cast<const float4*>(w) + (size_t)c * 64;
          float d0 = 0.f, d1 = 0.f, d2 = 0.f, d3 = 0.f;
#pragma unroll
          for (int k4 = 0; k4 < 16; ++k4) {
            float4 a0 = znr[k4 * 4 + 0], b0 = wr4[k4 * 4 + 0];
            float4 a1 = znr[k4 * 4 + 1], b1 = wr4[k4 * 4 + 1];
            float4 a2 = znr[k4 * 4 + 2], b2 = wr4[k4 * 4 + 2];
            float4 a3 = znr[k4 * 4 + 3], b3 = wr4[k4 * 4 + 3];
            d0 = fmaf(a0.x, b0.x, d0); d0 = fmaf(a0.y, b0.y, d0);
            d0 = fmaf(a0.z, b0.z, d0); d0 = fmaf(a0.w, b0.w, d0);
            d1 = fmaf(a1.x, b1.x, d1); d1 = fmaf(a1.y, b1.y, d1);
            d1 = fmaf(a1.z, b1.z, d1); d1 = fmaf(a1.w, b1.w, d1);
            d2 = fmaf(a2.x, b2.x, d2); d2 = fmaf(a2.y, b2.y, d2);
            d2 = fmaf(a2.z, b2.z, d2); d2 = fmaf(a2.w, b2.w, d2);
            d3 = fmaf(a3.x, b3.x, d3); d3 = fmaf(a3.y, b3.y, d3);
            d3 = fmaf(a3.z, b3.z, d3); d3 = fmaf(a3.w, b3.w, d3);
          }
          float dot = (d0 + d1) + (d2 + d3);
          float d = fmaf(-2.0f, dot, wn2[c]);
          if (d < bd || (d == bd && c < bi)) { bd = d; bi = c; }
        }
      }
    }
#pragma unroll
    for (int msk = 1; msk < 64; msk <<= 1) {
      float od = __shfl_xor(bd, msk, 64);
      int   oi = __shfl_xor(bi, msk, 64);
      if (od < bd || (od == bd && oi < bi)) { bd = od; bi = oi; }
    }
    if ((tid & 63) == 0) { wd[tid >> 6] = bd; wi[tid >> 6] = bi; }
    __syncthreads();
    if (tid == 0) {
      float fd = wd[0]; int fi = wi[0];
      if (wd[1] < fd || (wd[1] == fd && wi[1] < fi)) { fd = wd[1]; fi = wi[1]; }
      idxf[row] = fi;
    }
  }
}

// ---------------- kernel 6: gather + loss partials (atomic-free) ----------------
__global__ __launch_bounds__(256) void k_gather(const float* __restrict__ zn,
                                                const float* __restrict__ w,
                                                const int* __restrict__ idxf,
                                                float* __restrict__ zq,
                                                float* __restrict__ idx_out,
                                                float* __restrict__ wpart) {
  const int row  = blockIdx.x * 4 + (threadIdx.x >> 6);
  const int lane = threadIdx.x & 63;
  const int bi = idxf[row];
  float4 cv = *(reinterpret_cast<const float4*>(w)  + (size_t)bi  * 64 + lane);
  float4 zv = *(reinterpret_cast<const float4*>(zn) + (size_t)row * 64 + lane);
  *(reinterpret_cast<float4*>(zq) + (size_t)row * 64 + lane) = cv;
  float dx = cv.x - zv.x, dy = cv.y - zv.y, dz = cv.z - zv.z, dw = cv.w - zv.w;
  float s = dx * dx + dy * dy + dz * dz + dw * dw;
#pragma unroll
  for (int o = 32; o > 0; o >>= 1) s += __shfl_xor(s, o, 64);
  if (lane == 0) {
    wpart[row] = s;
    idx_out[row] = (float)bi;
  }
}

// ---------------- kernel 7: final loss reduction ----------------
__global__ __launch_bounds__(256) void k_final(const float* __restrict__ wpart,
                                               float* __restrict__ loss_out) {
  __shared__ float wsum[4];
  float s = 0.f;
  for (int i = threadIdx.x; i < BT_; i += 256) s += wpart[i];
#pragma unroll
  for (int o = 32; o > 0; o >>= 1) s += __shfl_xor(s, o, 64);
  if ((threadIdx.x & 63) == 0) wsum[threadIdx.x >> 6] = s;
  __syncthreads();
  if (threadIdx.x == 0)
    loss_out[0] = BETA_ * ((wsum[0] + wsum[1]) + (wsum[2] + wsum[3])) *
                  (1.0f / (float)(BT_ * D_));
}

extern "C" void kernel_launch(void* const* d_in, const int* in_sizes, int n_in,
                              void* d_out, int out_size, void* d_ws, size_t ws_size,
                              hipStream_t stream) {
  const float* z = (const float*)d_in[0];
  const float* w = (const float*)d_in[1];

  float* out      = (float*)d_out;
  float* zq       = out;
  float* loss_out = out + (size_t)BT_ * D_;
  float* idx_out  = loss_out + 1;

  char* wsb = (char*)d_ws;
  float*  zn      = (float*)(wsb);                         // 16 MB
  ushort* Acat    = (ushort*)(wsb + 16777216);             // 24 MB
  ushort* Bcat    = (ushort*)(wsb + 41943040);             // 12 MB
  float*  tm      = (float*)(wsb + 54525952);              // 2 MB used
  float*  ts      = (float*)(wsb + 58720256);              // 2 MB used (reused as wpart)
  int*    ti      = (int*)(wsb + 62914560);                // 2 MB used
  float*  wn2     = (float*)(wsb + 67108864);              // 32 KB
  int*    idxf    = (int*)(wsb + 67141632);                // 64 KB
  int*    flagged = (int*)(wsb + 67207168);                // 64 KB
  int*    count   = (int*)(wsb + 67272704);
  float*  wpart   = ts;   // ts is dead after k_combine

  hipFuncSetAttribute((const void*)k_coarse,
                      hipFuncAttributeMaxDynamicSharedMemorySize, 98304);

  hipMemsetAsync(count, 0, 4, stream);
  k_prep_z<<<BT_ / 4, 256, 0, stream>>>(z, zn, Acat);
  k_prep_w<<<N_ / 4, 256, 0, stream>>>(w, wn2, Bcat);
  k_coarse<<<(BT_ / BM) * NTILES, 512, 98304, stream>>>(Acat, Bcat, wn2, tm, ts, ti);
  k_combine<<<BT_ / 256, 256, 0, stream>>>(tm, ts, ti, idxf, flagged, count);
  k_refine<<<2048, 128, 0, stream>>>(zn, w, wn2, tm, flagged, count, idxf);
  k_gather<<<BT_ / 4, 256, 0, stream>>>(zn, w, idxf, zq, idx_out, wpart);
  k_final<<<1, 256, 0, stream>>>(wpart, loss_out);
}

// Round 5
// 409.495 us; speedup vs baseline: 1.0433x; 1.0433x over previous
//
#include <hip/hip_runtime.h>
#include <float.h>
#include <math.h>

// NormEMAVectorQuantizer via split-bf16 MFMA + exact fp32 refinement.
// z (8,2048,256) f32, weight (8192,256) f32 (unit rows).
// out = [ z_q (16384*256) | loss (1) | indices (16384, as float) ]
//
// Round-5 k_coarse: 256x256 tile, BK=64 (128B LDS rows -> r2-proven XOR
// swizzle), 8 waves (2Mx4N, 128x64 each), DOUBLE-buffered 128KB LDS,
// 4 phases per K-tile (16 MFMA each), 2 global_load_lds per phase.
// Staging calendar (race-free by region-free-time analysis):
//   tile t, p0/p1: stage A(t+1) (other buffer, idle all tile)
//   tile t, p2/p3: stage B(t+2) (own B buffer; B fully read at p0)
// vmcnt(4) before each tile's closing barrier (vmcnt(0) only tile 10).

#define BT_ 16384
#define D_  256
#define N_  8192
#define BETA_ 1.0f
#define THR_ 5e-4f

#define BM 256
#define BN 256
#define NKT 12           // 768 / 64 K-tiles
#define NTILES 32        // N_ / BN

typedef __attribute__((ext_vector_type(8))) short bf16x8;
typedef __attribute__((ext_vector_type(4))) float f32x4;

__device__ __forceinline__ void gld16(void* lds, const void* g) {
  __builtin_amdgcn_global_load_lds(
      (const __attribute__((address_space(1))) void*)g,
      (__attribute__((address_space(3))) void*)lds, 16, 0, 0);
}

__device__ __forceinline__ unsigned short f2bf(float x) {
  unsigned u = __float_as_uint(x);
  u += 0x7FFFu + ((u >> 16) & 1u);
  return (unsigned short)(u >> 16);
}
__device__ __forceinline__ float bf2f(unsigned short h) {
  return __uint_as_float(((unsigned)h) << 16);
}

// ---------------- kernel 1: normalize z, store zn + split A_cat ----------------
__global__ __launch_bounds__(256) void k_prep_z(const float* __restrict__ z,
                                                float* __restrict__ zn,
                                                ushort* __restrict__ Acat) {
  const int row  = blockIdx.x * 4 + (threadIdx.x >> 6);
  const int lane = threadIdx.x & 63;
  float4 v = *(reinterpret_cast<const float4*>(z) + (size_t)row * 64 + lane);
  float s = v.x * v.x + v.y * v.y + v.z * v.z + v.w * v.w;
#pragma unroll
  for (int o = 32; o > 0; o >>= 1) s += __shfl_xor(s, o, 64);
  float dn = fmaxf(sqrtf(s), 1e-12f);
  v.x /= dn; v.y /= dn; v.z /= dn; v.w /= dn;
  *(reinterpret_cast<float4*>(zn) + (size_t)row * 64 + lane) = v;
  ushort4 h  = make_ushort4(f2bf(v.x), f2bf(v.y), f2bf(v.z), f2bf(v.w));
  ushort4 lo = make_ushort4(f2bf(v.x - bf2f(h.x)), f2bf(v.y - bf2f(h.y)),
                            f2bf(v.z - bf2f(h.z)), f2bf(v.w - bf2f(h.w)));
  ushort4* A4 = reinterpret_cast<ushort4*>(Acat);
  size_t rb = (size_t)row * 192 + lane;   // 768/4 = 192 ushort4 per row
  A4[rb]       = h;    // zh
  A4[rb + 64]  = h;    // zh
  A4[rb + 128] = lo;   // zl
}

// ---------------- kernel 2: wn2, split B_cat ----------------
__global__ __launch_bounds__(256) void k_prep_w(const float* __restrict__ w,
                                                float* __restrict__ wn2,
                                                ushort* __restrict__ Bcat) {
  const int row  = blockIdx.x * 4 + (threadIdx.x >> 6);
  const int lane = threadIdx.x & 63;
  float4 v = *(reinterpret_cast<const float4*>(w) + (size_t)row * 64 + lane);
  float s = v.x * v.x + v.y * v.y + v.z * v.z + v.w * v.w;
#pragma unroll
  for (int o = 32; o > 0; o >>= 1) s += __shfl_xor(s, o, 64);
  if (lane == 0) wn2[row] = s;
  ushort4 h  = make_ushort4(f2bf(v.x), f2bf(v.y), f2bf(v.z), f2bf(v.w));
  ushort4 lo = make_ushort4(f2bf(v.x - bf2f(h.x)), f2bf(v.y - bf2f(h.y)),
                            f2bf(v.z - bf2f(h.z)), f2bf(v.w - bf2f(h.w)));
  ushort4* B4 = reinterpret_cast<ushort4*>(Bcat);
  size_t rb = (size_t)row * 192 + lane;
  B4[rb]       = h;    // wh
  B4[rb + 64]  = lo;   // wl
  B4[rb + 128] = h;    // wh
}

// ---------------- kernel 3: 8-phase-style MFMA GEMM, 256x256, BK=64 ---------
// grid = 64 rt x 32 ct = 2048 blocks, 512 threads (8 waves, 2M x 4N).
// LDS (dynamic 128KB): A bufs @0,@32K; B bufs @64K,@96K. [256 rows][128B]
// LDS swizzle (proven r2, 65K conflicts): LDS[r][g16] = G[r][g16 ^ (r&7)].
__global__ __launch_bounds__(512, 2) void k_coarse(const ushort* __restrict__ Acat,
                                                   const ushort* __restrict__ Bcat,
                                                   const float* __restrict__ wn2,
                                                   float* __restrict__ tm,
                                                   float* __restrict__ ts,
                                                   int* __restrict__ ti) {
  extern __shared__ char smem[];

  const int tid = threadIdx.x;
  const int l   = tid & 63;
  const int wv  = tid >> 6;
  const int wr  = wv >> 2;       // 0..1 -> rows wr*128
  const int wc  = wv & 3;        // 0..3 -> cols wc*64
  // XCD-aware 2D-chunked swizzle (r4-proven: FETCH 427->142MB)
  const int bid  = blockIdx.x;
  const int xcd  = bid & 7;
  const int q    = bid >> 3;
  const int chnk = q >> 5, wq = q & 31;
  const int rt   = xcd * 8 + (chnk >> 2) * 4 + (wq >> 3);
  const int ct   = (chnk & 3) * 8 + (wq & 7);
  const int row0 = rt * BM;
  const int col0 = ct * BN;

  // staging source (pre-swizzled): wave wv stages rows [u*64+wv*8, +8) per call;
  // lane l -> row u*64+wv*8+(l>>3), source 16B-granule (l&7)^((l>>3)&7).
  const int srow = l >> 3;
  const int sg   = ((l & 7) ^ srow) * 16;
  const char* aS = (const char*)Acat + (size_t)(row0 + wv * 8 + srow) * 1536 + sg;
  const char* bS = (const char*)Bcat + (size_t)(col0 + wv * 8 + srow) * 1536 + sg;

  // fragment read offsets: row R byte base R*128; k-granule (l>>4)+ks*4,
  // swizzled by (R&7) = (lA&7).
  const int lA   = l & 15;
  const int kswz = (lA & 7) << 4;
  const int kof0 = ((l >> 4) * 16) ^ kswz;
  const int kof1 = (((l >> 4) * 16) + 64) ^ kswz;
  const int aRow = (wr * 128 + lA) * 128;   // + m*2048 + ab
  const int bRow = (wc * 64  + lA) * 128;   // + n*2048 + bb

  f32x4 acc[8][4];
#pragma unroll
  for (int i = 0; i < 8; ++i)
#pragma unroll
    for (int j = 0; j < 4; ++j) acc[i][j] = (f32x4){0.f, 0.f, 0.f, 0.f};

  // prologue: A(0) 4 units, B(0) 4 units, B(1) 4 units (12 loads/thread)
#pragma unroll
  for (int u = 0; u < 4; ++u)
    gld16(smem + u * 8192 + wv * 1024, aS + (size_t)u * 98304);
#pragma unroll
  for (int u = 0; u < 4; ++u)
    gld16(smem + 65536 + u * 8192 + wv * 1024, bS + (size_t)u * 98304);
#pragma unroll
  for (int u = 0; u < 4; ++u)
    gld16(smem + 98304 + u * 8192 + wv * 1024, bS + (size_t)u * 98304 + 128);
  asm volatile("s_waitcnt vmcnt(4)" ::: "memory");   // A(0),B(0) arrived
  __builtin_amdgcn_s_barrier();

  for (int t = 0; t < NKT; ++t) {
    const int ab = (t & 1) * 32768;
    const int bb = 65536 + ab;
    bf16x8 bg[4][2];
#pragma unroll
    for (int p = 0; p < 4; ++p) {
      const int m0 = 2 * p, m1 = 2 * p + 1;
      // ds-reads for this phase
      bf16x8 a00 = *(const bf16x8*)(smem + ab + aRow + m0 * 2048 + kof0);
      bf16x8 a01 = *(const bf16x8*)(smem + ab + aRow + m0 * 2048 + kof1);
      bf16x8 a10 = *(const bf16x8*)(smem + ab + aRow + m1 * 2048 + kof0);
      bf16x8 a11 = *(const bf16x8*)(smem + ab + aRow + m1 * 2048 + kof1);
      if (p == 0) {
#pragma unroll
        for (int n = 0; n < 4; ++n) {
          bg[n][0] = *(const bf16x8*)(smem + bb + bRow + n * 2048 + kof0);
          bg[n][1] = *(const bf16x8*)(smem + bb + bRow + n * 2048 + kof1);
        }
      }
      // staging: 2 loads/phase
      if (p == 0 && t + 1 < NKT) {
        gld16(smem + ((t + 1) & 1) * 32768 + wv * 1024,        aS + (size_t)(t + 1) * 128);
        gld16(smem + ((t + 1) & 1) * 32768 + 8192 + wv * 1024, aS + 98304 + (size_t)(t + 1) * 128);
      } else if (p == 1 && t + 1 < NKT) {
        gld16(smem + ((t + 1) & 1) * 32768 + 16384 + wv * 1024, aS + 196608 + (size_t)(t + 1) * 128);
        gld16(smem + ((t + 1) & 1) * 32768 + 24576 + wv * 1024, aS + 294912 + (size_t)(t + 1) * 128);
      } else if (p == 2 && t + 2 < NKT) {
        gld16(smem + bb + wv * 1024,        bS + (size_t)(t + 2) * 128);
        gld16(smem + bb + 8192 + wv * 1024, bS + 98304 + (size_t)(t + 2) * 128);
      } else if (p == 3 && t + 2 < NKT) {
        gld16(smem + bb + 16384 + wv * 1024, bS + 196608 + (size_t)(t + 2) * 128);
        gld16(smem + bb + 24576 + wv * 1024, bS + 294912 + (size_t)(t + 2) * 128);
      }
      __builtin_amdgcn_s_barrier();
      asm volatile("s_waitcnt lgkmcnt(0)" ::: "memory");
      __builtin_amdgcn_s_setprio(1);
#pragma unroll
      for (int n = 0; n < 4; ++n)
        acc[m0][n] = __builtin_amdgcn_mfma_f32_16x16x32_bf16(a00, bg[n][0], acc[m0][n], 0, 0, 0);
#pragma unroll
      for (int n = 0; n < 4; ++n)
        acc[m1][n] = __builtin_amdgcn_mfma_f32_16x16x32_bf16(a10, bg[n][0], acc[m1][n], 0, 0, 0);
#pragma unroll
      for (int n = 0; n < 4; ++n)
        acc[m0][n] = __builtin_amdgcn_mfma_f32_16x16x32_bf16(a01, bg[n][1], acc[m0][n], 0, 0, 0);
#pragma unroll
      for (int n = 0; n < 4; ++n)
        acc[m1][n] = __builtin_amdgcn_mfma_f32_16x16x32_bf16(a11, bg[n][1], acc[m1][n], 0, 0, 0);
      __builtin_amdgcn_s_setprio(0);
      if (p == 3) {
        if (t < NKT - 2)       asm volatile("s_waitcnt vmcnt(4)" ::: "memory");
        else if (t == NKT - 2) asm volatile("s_waitcnt vmcnt(0)" ::: "memory");
      }
      __builtin_amdgcn_s_barrier();
    }
  }

  // epilogue: reuse dynamic LDS for the reduction scratch.
  float* red_m = (float*)(smem);            // [256][4]
  float* red_s = (float*)(smem + 4096);     // [256][4]
  int*   red_i = (int*)(smem + 8192);       // [256][4]
  float wnv[4];
#pragma unroll
  for (int n = 0; n < 4; ++n) wnv[n] = wn2[col0 + wc * 64 + n * 16 + lA];

  // C layout (16x16x32): col = lane&15, row = (lane>>4)*4 + reg
#pragma unroll
  for (int i = 0; i < 8; ++i) {
#pragma unroll
    for (int qq = 0; qq < 4; ++qq) {
      float m = FLT_MAX, s = FLT_MAX; int bi = 0;
#pragma unroll
      for (int j = 0; j < 4; ++j) {
        float d = fmaf(-2.0f, acc[i][j][qq], wnv[j]);
        int c = col0 + wc * 64 + j * 16 + lA;
        if (d < m) { s = m; m = d; bi = c; }
        else if (d < s) { s = d; }
      }
#pragma unroll
      for (int msk = 1; msk < 16; msk <<= 1) {
        float om = __shfl_xor(m, msk, 64);
        float os = __shfl_xor(s, msk, 64);
        int   oi = __shfl_xor(bi, msk, 64);
        float nsv = fminf(fminf(s, os), fmaxf(m, om));
        if (om < m || (om == m && oi < bi)) { m = om; bi = oi; }
        s = nsv;
      }
      if (lA == 0) {
        int rl = wr * 128 + i * 16 + (l >> 4) * 4 + qq;
        red_m[rl * 4 + wc] = m; red_s[rl * 4 + wc] = s; red_i[rl * 4 + wc] = bi;
      }
    }
  }
  __syncthreads();
  if (tid < BM) {
    float m = red_m[tid * 4], s = red_s[tid * 4]; int bi = red_i[tid * 4];
#pragma unroll
    for (int k = 1; k < 4; ++k) {
      float om = red_m[tid * 4 + k], os = red_s[tid * 4 + k]; int oi = red_i[tid * 4 + k];
      float nsv = fminf(fminf(s, os), fmaxf(m, om));
      if (om < m || (om == m && oi < bi)) { m = om; bi = oi; }
      s = nsv;
    }
    size_t o = (size_t)ct * BT_ + row0 + tid;
    tm[o] = m; ts[o] = s; ti[o] = bi;
  }
}

// ---------------- kernel 4: combine tiles per row, flag ambiguous ----------------
__global__ __launch_bounds__(256) void k_combine(const float* __restrict__ tm,
                                                 const float* __restrict__ ts,
                                                 const int* __restrict__ ti,
                                                 int* __restrict__ idxf,
                                                 int* __restrict__ flagged,
                                                 int* __restrict__ count) {
  const int row = blockIdx.x * 256 + threadIdx.x;
  float m = FLT_MAX, s = FLT_MAX; int bi = 0x7fffffff;
  for (int t = 0; t < NTILES; ++t) {
    size_t o = (size_t)t * BT_ + row;
    float om = tm[o], os = ts[o]; int oi = ti[o];
    float nsv = fminf(fminf(s, os), fmaxf(m, om));
    if (om < m || (om == m && oi < bi)) { m = om; bi = oi; }
    s = nsv;
  }
  idxf[row] = bi;
  if (s - m <= THR_) {
    int p = atomicAdd(count, 1);
    flagged[p] = row;
  }
}

// ---------------- kernel 5: exact fp32 refinement of flagged rows ----------------
// 2048 blocks x 128 threads; one flagged row per block (grid-stride).
__global__ __launch_bounds__(128) void k_refine(const float* __restrict__ zn,
                                                const float* __restrict__ w,
                                                const float* __restrict__ wn2,
                                                const float* __restrict__ tm,
                                                const int* __restrict__ flagged,
                                                const int* __restrict__ count,
                                                int* __restrict__ idxf) {
  __shared__ float4 znr[64];
  __shared__ float tmr[32];
  __shared__ float m1s;
  __shared__ float wd[2];
  __shared__ int   wi[2];
  const int tid = threadIdx.x;
  const int cnt = *count;
  for (int f = blockIdx.x; f < cnt; f += gridDim.x) {
    __syncthreads();   // protect LDS reuse across iterations
    const int row = flagged[f];
    if (tid < 64) {
      znr[tid] = *(reinterpret_cast<const float4*>(zn) + (size_t)row * 64 + tid);
    }
    if (tid < 32) {
      float tv = tm[(size_t)tid * BT_ + row];
      tmr[tid] = tv;
      float mm = tv;
#pragma unroll
      for (int msk = 16; msk > 0; msk >>= 1) mm = fminf(mm, __shfl_xor(mm, msk, 64));
      if (tid == 0) m1s = mm;
    }
    __syncthreads();
    const float lim = m1s + THR_;
    float bd = FLT_MAX; int bi = 0x7fffffff;
    for (int t = 0; t < NTILES; ++t) {
      if (tmr[t] <= lim) {
#pragma unroll
        for (int h = 0; h < 2; ++h) {
          int c = t * BN + h * 128 + tid;
          const float4* wr4 = reinterpret_cast<const float4*>(w) + (size_t)c * 64;
          float d0 = 0.f, d1 = 0.f, d2 = 0.f, d3 = 0.f;
#pragma unroll
          for (int k4 = 0; k4 < 16; ++k4) {
            float4 a0 = znr[k4 * 4 + 0], b0 = wr4[k4 * 4 + 0];
            float4 a1 = znr[k4 * 4 + 1], b1 = wr4[k4 * 4 + 1];
            float4 a2 = znr[k4 * 4 + 2], b2 = wr4[k4 * 4 + 2];
            float4 a3 = znr[k4 * 4 + 3], b3 = wr4[k4 * 4 + 3];
            d0 = fmaf(a0.x, b0.x, d0); d0 = fmaf(a0.y, b0.y, d0);
            d0 = fmaf(a0.z, b0.z, d0); d0 = fmaf(a0.w, b0.w, d0);
            d1 = fmaf(a1.x, b1.x, d1); d1 = fmaf(a1.y, b1.y, d1);
            d1 = fmaf(a1.z, b1.z, d1); d1 = fmaf(a1.w, b1.w, d1);
            d2 = fmaf(a2.x, b2.x, d2); d2 = fmaf(a2.y, b2.y, d2);
            d2 = fmaf(a2.z, b2.z, d2); d2 = fmaf(a2.w, b2.w, d2);
            d3 = fmaf(a3.x, b3.x, d3); d3 = fmaf(a3.y, b3.y, d3);
            d3 = fmaf(a3.z, b3.z, d3); d3 = fmaf(a3.w, b3.w, d3);
          }
          float dot = (d0 + d1) + (d2 + d3);
          float d = fmaf(-2.0f, dot, wn2[c]);
          if (d < bd || (d == bd && c < bi)) { bd = d; bi = c; }
        }
      }
    }
#pragma unroll
    for (int msk = 1; msk < 64; msk <<= 1) {
      float od = __shfl_xor(bd, msk, 64);
      int   oi = __shfl_xor(bi, msk, 64);
      if (od < bd || (od == bd && oi < bi)) { bd = od; bi = oi; }
    }
    if ((tid & 63) == 0) { wd[tid >> 6] = bd; wi[tid >> 6] = bi; }
    __syncthreads();
    if (tid == 0) {
      float fd = wd[0]; int fi = wi[0];
      if (wd[1] < fd || (wd[1] == fd && wi[1] < fi)) { fd = wd[1]; fi = wi[1]; }
      idxf[row] = fi;
    }
  }
}

// ---------------- kernel 6: gather + loss partials (atomic-free) ----------------
__global__ __launch_bounds__(256) void k_gather(const float* __restrict__ zn,
                                                const float* __restrict__ w,
                                                const int* __restrict__ idxf,
                                                float* __restrict__ zq,
                                                float* __restrict__ idx_out,
                                                float* __restrict__ wpart) {
  const int row  = blockIdx.x * 4 + (threadIdx.x >> 6);
  const int lane = threadIdx.x & 63;
  const int bi = idxf[row];
  float4 cv = *(reinterpret_cast<const float4*>(w)  + (size_t)bi  * 64 + lane);
  float4 zv = *(reinterpret_cast<const float4*>(zn) + (size_t)row * 64 + lane);
  *(reinterpret_cast<float4*>(zq) + (size_t)row * 64 + lane) = cv;
  float dx = cv.x - zv.x, dy = cv.y - zv.y, dz = cv.z - zv.z, dw = cv.w - zv.w;
  float s = dx * dx + dy * dy + dz * dz + dw * dw;
#pragma unroll
  for (int o = 32; o > 0; o >>= 1) s += __shfl_xor(s, o, 64);
  if (lane == 0) {
    wpart[row] = s;
    idx_out[row] = (float)bi;
  }
}

// ---------------- kernel 7: final loss reduction ----------------
__global__ __launch_bounds__(256) void k_final(const float* __restrict__ wpart,
                                               float* __restrict__ loss_out) {
  __shared__ float wsum[4];
  float s = 0.f;
  for (int i = threadIdx.x; i < BT_; i += 256) s += wpart[i];
#pragma unroll
  for (int o = 32; o > 0; o >>= 1) s += __shfl_xor(s, o, 64);
  if ((threadIdx.x & 63) == 0) wsum[threadIdx.x >> 6] = s;
  __syncthreads();
  if (threadIdx.x == 0)
    loss_out[0] = BETA_ * ((wsum[0] + wsum[1]) + (wsum[2] + wsum[3])) *
                  (1.0f / (float)(BT_ * D_));
}

extern "C" void kernel_launch(void* const* d_in, const int* in_sizes, int n_in,
                              void* d_out, int out_size, void* d_ws, size_t ws_size,
                              hipStream_t stream) {
  const float* z = (const float*)d_in[0];
  const float* w = (const float*)d_in[1];

  float* out      = (float*)d_out;
  float* zq       = out;
  float* loss_out = out + (size_t)BT_ * D_;
  float* idx_out  = loss_out + 1;

  char* wsb = (char*)d_ws;
  float*  zn      = (float*)(wsb);                         // 16 MB
  ushort* Acat    = (ushort*)(wsb + 16777216);             // 24 MB
  ushort* Bcat    = (ushort*)(wsb + 41943040);             // 12 MB
  float*  tm      = (float*)(wsb + 54525952);              // 2 MB used
  float*  ts      = (float*)(wsb + 58720256);              // 2 MB used (reused as wpart)
  int*    ti      = (int*)(wsb + 62914560);                // 2 MB used
  float*  wn2     = (float*)(wsb + 67108864);              // 32 KB
  int*    idxf    = (int*)(wsb + 67141632);                // 64 KB
  int*    flagged = (int*)(wsb + 67207168);                // 64 KB
  int*    count   = (int*)(wsb + 67272704);
  float*  wpart   = ts;   // ts is dead after k_combine

  hipFuncSetAttribute((const void*)k_coarse,
                      hipFuncAttributeMaxDynamicSharedMemorySize, 131072);

  hipMemsetAsync(count, 0, 4, stream);
  k_prep_z<<<BT_ / 4, 256, 0, stream>>>(z, zn, Acat);
  k_prep_w<<<N_ / 4, 256, 0, stream>>>(w, wn2, Bcat);
  k_coarse<<<(BT_ / BM) * NTILES, 512, 131072, stream>>>(Acat, Bcat, wn2, tm, ts, ti);
  k_combine<<<BT_ / 256, 256, 0, stream>>>(tm, ts, ti, idxf, flagged, count);
  k_refine<<<2048, 128, 0, stream>>>(zn, w, wn2, tm, flagged, count, idxf);
  k_gather<<<BT_ / 4, 256, 0, stream>>>(zn, w, idxf, zq, idx_out, wpart);
  k_final<<<1, 256, 0, stream>>>(wpart, loss_out);
}

// Round 6
// 382.997 us; speedup vs baseline: 1.1155x; 1.0692x over previous
//
#include <hip/hip_runtime.h>
#include <float.h>
#include <math.h>

// NormEMAVectorQuantizer via split-bf16 MFMA + exact fp32 refinement.
// z (8,2048,256) f32, weight (8192,256) f32 (unit rows).
// out = [ z_q (16384*256) | loss (1) | indices (16384, as float) ]
//
// Round-6: (a) fragment loads are inline-asm ds_read_b128 pinned BEFORE the
// phase barrier with sched_barrier(0) fences (rule 18) so LDS reads overlap
// other waves' MFMA through the queue; (b) epilogue rewritten as 2-round LDS
// scatter/scan (no shuffle butterflies). Geometry/staging calendar = r5
// (256x256, BK=64, 8 waves 2Mx4N, double-buffer 128KB, vmcnt(4) counted).

#define BT_ 16384
#define D_  256
#define N_  8192
#define BETA_ 1.0f
#define THR_ 5e-4f

#define BM 256
#define BN 256
#define NKT 12           // 768 / 64 K-tiles
#define NTILES 32        // N_ / BN

typedef __attribute__((ext_vector_type(8))) short bf16x8;
typedef __attribute__((ext_vector_type(4))) float f32x4;
typedef __attribute__((ext_vector_type(8))) unsigned short u16x8;

__device__ __forceinline__ void gld16(void* lds, const void* g) {
  __builtin_amdgcn_global_load_lds(
      (const __attribute__((address_space(1))) void*)g,
      (__attribute__((address_space(3))) void*)lds, 16, 0, 0);
}

// pinned LDS read: issues exactly where written (volatile asm)
__device__ __forceinline__ bf16x8 dsr(unsigned addr) {
  bf16x8 r;
  asm volatile("ds_read_b128 %0, %1" : "=&v"(r) : "v"(addr));
  return r;
}

__device__ __forceinline__ unsigned short f2bf(float x) {
  unsigned u = __float_as_uint(x);
  u += 0x7FFFu + ((u >> 16) & 1u);
  return (unsigned short)(u >> 16);
}
__device__ __forceinline__ float bf2f(unsigned short h) {
  return __uint_as_float(((unsigned)h) << 16);
}

// ---------------- kernel 1: normalize z, store zn + split A_cat ----------------
__global__ __launch_bounds__(256) void k_prep_z(const float* __restrict__ z,
                                                float* __restrict__ zn,
                                                ushort* __restrict__ Acat) {
  const int row  = blockIdx.x * 4 + (threadIdx.x >> 6);
  const int lane = threadIdx.x & 63;
  float4 v = *(reinterpret_cast<const float4*>(z) + (size_t)row * 64 + lane);
  float s = v.x * v.x + v.y * v.y + v.z * v.z + v.w * v.w;
#pragma unroll
  for (int o = 32; o > 0; o >>= 1) s += __shfl_xor(s, o, 64);
  float dn = fmaxf(sqrtf(s), 1e-12f);
  v.x /= dn; v.y /= dn; v.z /= dn; v.w /= dn;
  *(reinterpret_cast<float4*>(zn) + (size_t)row * 64 + lane) = v;
  ushort4 h  = make_ushort4(f2bf(v.x), f2bf(v.y), f2bf(v.z), f2bf(v.w));
  ushort4 lo = make_ushort4(f2bf(v.x - bf2f(h.x)), f2bf(v.y - bf2f(h.y)),
                            f2bf(v.z - bf2f(h.z)), f2bf(v.w - bf2f(h.w)));
  ushort4* A4 = reinterpret_cast<ushort4*>(Acat);
  size_t rb = (size_t)row * 192 + lane;   // 768/4 = 192 ushort4 per row
  A4[rb]       = h;    // zh
  A4[rb + 64]  = h;    // zh
  A4[rb + 128] = lo;   // zl
}

// ---------------- kernel 2: wn2, split B_cat ----------------
__global__ __launch_bounds__(256) void k_prep_w(const float* __restrict__ w,
                                                float* __restrict__ wn2,
                                                ushort* __restrict__ Bcat) {
  const int row  = blockIdx.x * 4 + (threadIdx.x >> 6);
  const int lane = threadIdx.x & 63;
  float4 v = *(reinterpret_cast<const float4*>(w) + (size_t)row * 64 + lane);
  float s = v.x * v.x + v.y * v.y + v.z * v.z + v.w * v.w;
#pragma unroll
  for (int o = 32; o > 0; o >>= 1) s += __shfl_xor(s, o, 64);
  if (lane == 0) wn2[row] = s;
  ushort4 h  = make_ushort4(f2bf(v.x), f2bf(v.y), f2bf(v.z), f2bf(v.w));
  ushort4 lo = make_ushort4(f2bf(v.x - bf2f(h.x)), f2bf(v.y - bf2f(h.y)),
                            f2bf(v.z - bf2f(h.z)), f2bf(v.w - bf2f(h.w)));
  ushort4* B4 = reinterpret_cast<ushort4*>(Bcat);
  size_t rb = (size_t)row * 192 + lane;
  B4[rb]       = h;    // wh
  B4[rb + 64]  = lo;   // wl
  B4[rb + 128] = h;    // wh
}

// ---------------- kernel 3: pinned 4-phase MFMA GEMM, 256x256, BK=64 --------
// grid = 2048 blocks, 512 threads (8 waves, 2M x 4N, 128x64 out each).
// LDS (dynamic 128KB): A bufs @0,@32K; B bufs @64K,@96K. [256 rows][128B].
// Swizzle: LDS[r][g16] = G[r][g16 ^ (r&7)] (both sides, r2-proven).
__global__ __launch_bounds__(512, 2) void k_coarse(const ushort* __restrict__ Acat,
                                                   const ushort* __restrict__ Bcat,
                                                   const float* __restrict__ wn2,
                                                   float* __restrict__ tm,
                                                   float* __restrict__ ts,
                                                   int* __restrict__ ti) {
  extern __shared__ char smem[];
  const unsigned sbase = (unsigned)(size_t)(void*)smem & 0x3ffffu;  // LDS byte base

  const int tid = threadIdx.x;
  const int l   = tid & 63;
  const int wv  = tid >> 6;
  const int wr  = wv >> 2;       // 0..1 -> rows wr*128
  const int wc  = wv & 3;        // 0..3 -> cols wc*64
  // XCD-aware 2D-chunked swizzle (r4-proven: FETCH 427->142MB)
  const int bid  = blockIdx.x;
  const int xcd  = bid & 7;
  const int q    = bid >> 3;
  const int chnk = q >> 5, wq = q & 31;
  const int rt   = xcd * 8 + (chnk >> 2) * 4 + (wq >> 3);
  const int ct   = (chnk & 3) * 8 + (wq & 7);
  const int row0 = rt * BM;
  const int col0 = ct * BN;

  // staging source (pre-swizzled): wave wv stages rows [u*64+wv*8, +8)/unit;
  // lane l -> row +(l>>3), source 16B-granule (l&7)^(l>>3).
  const int srow = l >> 3;
  const int sg   = ((l & 7) ^ srow) * 16;
  const char* aS = (const char*)Acat + (size_t)(row0 + wv * 8 + srow) * 1536 + sg;
  const char* bS = (const char*)Bcat + (size_t)(col0 + wv * 8 + srow) * 1536 + sg;

  // fragment read offsets: row R byte base R*128; granule swizzled by (R&7)
  const int lA   = l & 15;
  const int kswz = (lA & 7) << 4;
  const int kof0 = ((l >> 4) * 16) ^ kswz;
  const int kof1 = (((l >> 4) * 16) + 64) ^ kswz;
  const unsigned aRow = (unsigned)((wr * 128 + lA) * 128);
  const unsigned bRow = (unsigned)((wc * 64  + lA) * 128);

  f32x4 acc[8][4];
#pragma unroll
  for (int i = 0; i < 8; ++i)
#pragma unroll
    for (int j = 0; j < 4; ++j) acc[i][j] = (f32x4){0.f, 0.f, 0.f, 0.f};

  // prologue: A(0) 4 units, B(0) 4 units, B(1) 4 units
#pragma unroll
  for (int u = 0; u < 4; ++u)
    gld16(smem + u * 8192 + wv * 1024, aS + (size_t)u * 98304);
#pragma unroll
  for (int u = 0; u < 4; ++u)
    gld16(smem + 65536 + u * 8192 + wv * 1024, bS + (size_t)u * 98304);
#pragma unroll
  for (int u = 0; u < 4; ++u)
    gld16(smem + 98304 + u * 8192 + wv * 1024, bS + (size_t)u * 98304 + 128);
  asm volatile("s_waitcnt vmcnt(4)" ::: "memory");   // A(0),B(0) arrived
  __builtin_amdgcn_sched_barrier(0);
  __builtin_amdgcn_s_barrier();

  for (int t = 0; t < NKT; ++t) {
    const unsigned ab = (unsigned)((t & 1) * 32768);
    const unsigned bb = 65536u + ab;
    const unsigned nb = (unsigned)(((t + 1) & 1) * 32768);
    bf16x8 bg00, bg01, bg10, bg11, bg20, bg21, bg30, bg31;

#define MFMA16(A0K0, A0K1, A1K0, A1K1, M0, M1)                                  \
    acc[M0][0] = __builtin_amdgcn_mfma_f32_16x16x32_bf16(A0K0, bg00, acc[M0][0], 0, 0, 0); \
    acc[M0][1] = __builtin_amdgcn_mfma_f32_16x16x32_bf16(A0K0, bg10, acc[M0][1], 0, 0, 0); \
    acc[M0][2] = __builtin_amdgcn_mfma_f32_16x16x32_bf16(A0K0, bg20, acc[M0][2], 0, 0, 0); \
    acc[M0][3] = __builtin_amdgcn_mfma_f32_16x16x32_bf16(A0K0, bg30, acc[M0][3], 0, 0, 0); \
    acc[M1][0] = __builtin_amdgcn_mfma_f32_16x16x32_bf16(A1K0, bg00, acc[M1][0], 0, 0, 0); \
    acc[M1][1] = __builtin_amdgcn_mfma_f32_16x16x32_bf16(A1K0, bg10, acc[M1][1], 0, 0, 0); \
    acc[M1][2] = __builtin_amdgcn_mfma_f32_16x16x32_bf16(A1K0, bg20, acc[M1][2], 0, 0, 0); \
    acc[M1][3] = __builtin_amdgcn_mfma_f32_16x16x32_bf16(A1K0, bg30, acc[M1][3], 0, 0, 0); \
    acc[M0][0] = __builtin_amdgcn_mfma_f32_16x16x32_bf16(A0K1, bg01, acc[M0][0], 0, 0, 0); \
    acc[M0][1] = __builtin_amdgcn_mfma_f32_16x16x32_bf16(A0K1, bg11, acc[M0][1], 0, 0, 0); \
    acc[M0][2] = __builtin_amdgcn_mfma_f32_16x16x32_bf16(A0K1, bg21, acc[M0][2], 0, 0, 0); \
    acc[M0][3] = __builtin_amdgcn_mfma_f32_16x16x32_bf16(A0K1, bg31, acc[M0][3], 0, 0, 0); \
    acc[M1][0] = __builtin_amdgcn_mfma_f32_16x16x32_bf16(A1K1, bg01, acc[M1][0], 0, 0, 0); \
    acc[M1][1] = __builtin_amdgcn_mfma_f32_16x16x32_bf16(A1K1, bg11, acc[M1][1], 0, 0, 0); \
    acc[M1][2] = __builtin_amdgcn_mfma_f32_16x16x32_bf16(A1K1, bg21, acc[M1][2], 0, 0, 0); \
    acc[M1][3] = __builtin_amdgcn_mfma_f32_16x16x32_bf16(A1K1, bg31, acc[M1][3], 0, 0, 0)

    // ---------------- phase 0: m0,m1 + all B frags; stage A(t+1) u0,u1 ------
    {
      bf16x8 a00 = dsr(sbase + ab + aRow + 0 * 2048 + kof0);
      bf16x8 a01 = dsr(sbase + ab + aRow + 0 * 2048 + kof1);
      bf16x8 a10 = dsr(sbase + ab + aRow + 1 * 2048 + kof0);
      bf16x8 a11 = dsr(sbase + ab + aRow + 1 * 2048 + kof1);
      bg00 = dsr(sbase + bb + bRow + 0 * 2048 + kof0);
      bg01 = dsr(sbase + bb + bRow + 0 * 2048 + kof1);
      bg10 = dsr(sbase + bb + bRow + 1 * 2048 + kof0);
      bg11 = dsr(sbase + bb + bRow + 1 * 2048 + kof1);
      bg20 = dsr(sbase + bb + bRow + 2 * 2048 + kof0);
      bg21 = dsr(sbase + bb + bRow + 2 * 2048 + kof1);
      bg30 = dsr(sbase + bb + bRow + 3 * 2048 + kof0);
      bg31 = dsr(sbase + bb + bRow + 3 * 2048 + kof1);
      if (t + 1 < NKT) {
        gld16(smem + nb + wv * 1024,        aS + (size_t)(t + 1) * 128);
        gld16(smem + nb + 8192 + wv * 1024, aS + 98304 + (size_t)(t + 1) * 128);
      }
      asm volatile("s_waitcnt lgkmcnt(8)" ::: "memory");
      __builtin_amdgcn_sched_barrier(0);
      __builtin_amdgcn_s_barrier();
      asm volatile("s_waitcnt lgkmcnt(0)" ::: "memory");
      __builtin_amdgcn_sched_barrier(0);
      __builtin_amdgcn_s_setprio(1);
      MFMA16(a00, a01, a10, a11, 0, 1);
      __builtin_amdgcn_s_setprio(0);
      __builtin_amdgcn_sched_barrier(0);
      __builtin_amdgcn_s_barrier();
    }
    // ---------------- phase 1: m2,m3; stage A(t+1) u2,u3 --------------------
    {
      bf16x8 a00 = dsr(sbase + ab + aRow + 2 * 2048 + kof0);
      bf16x8 a01 = dsr(sbase + ab + aRow + 2 * 2048 + kof1);
      bf16x8 a10 = dsr(sbase + ab + aRow + 3 * 2048 + kof0);
      bf16x8 a11 = dsr(sbase + ab + aRow + 3 * 2048 + kof1);
      if (t + 1 < NKT) {
        gld16(smem + nb + 16384 + wv * 1024, aS + 196608 + (size_t)(t + 1) * 128);
        gld16(smem + nb + 24576 + wv * 1024, aS + 294912 + (size_t)(t + 1) * 128);
      }
      __builtin_amdgcn_sched_barrier(0);
      __builtin_amdgcn_s_barrier();
      asm volatile("s_waitcnt lgkmcnt(0)" ::: "memory");
      __builtin_amdgcn_sched_barrier(0);
      __builtin_amdgcn_s_setprio(1);
      MFMA16(a00, a01, a10, a11, 2, 3);
      __builtin_amdgcn_s_setprio(0);
      __builtin_amdgcn_sched_barrier(0);
      __builtin_amdgcn_s_barrier();
    }
    // ---------------- phase 2: m4,m5; stage B(t+2) u0,u1 --------------------
    {
      bf16x8 a00 = dsr(sbase + ab + aRow + 4 * 2048 + kof0);
      bf16x8 a01 = dsr(sbase + ab + aRow + 4 * 2048 + kof1);
      bf16x8 a10 = dsr(sbase + ab + aRow + 5 * 2048 + kof0);
      bf16x8 a11 = dsr(sbase + ab + aRow + 5 * 2048 + kof1);
      if (t + 2 < NKT) {
        gld16(smem + bb + wv * 1024,        bS + (size_t)(t + 2) * 128);
        gld16(smem + bb + 8192 + wv * 1024, bS + 98304 + (size_t)(t + 2) * 128);
      }
      __builtin_amdgcn_sched_barrier(0);
      __builtin_amdgcn_s_barrier();
      asm volatile("s_waitcnt lgkmcnt(0)" ::: "memory");
      __builtin_amdgcn_sched_barrier(0);
      __builtin_amdgcn_s_setprio(1);
      MFMA16(a00, a01, a10, a11, 4, 5);
      __builtin_amdgcn_s_setprio(0);
      __builtin_amdgcn_sched_barrier(0);
      __builtin_amdgcn_s_barrier();
    }
    // ---------------- phase 3: m6,m7; stage B(t+2) u2,u3; tile vmcnt --------
    {
      bf16x8 a00 = dsr(sbase + ab + aRow + 6 * 2048 + kof0);
      bf16x8 a01 = dsr(sbase + ab + aRow + 6 * 2048 + kof1);
      bf16x8 a10 = dsr(sbase + ab + aRow + 7 * 2048 + kof0);
      bf16x8 a11 = dsr(sbase + ab + aRow + 7 * 2048 + kof1);
      if (t + 2 < NKT) {
        gld16(smem + bb + 16384 + wv * 1024, bS + 196608 + (size_t)(t + 2) * 128);
        gld16(smem + bb + 24576 + wv * 1024, bS + 294912 + (size_t)(t + 2) * 128);
      }
      __builtin_amdgcn_sched_barrier(0);
      __builtin_amdgcn_s_barrier();
      asm volatile("s_waitcnt lgkmcnt(0)" ::: "memory");
      __builtin_amdgcn_sched_barrier(0);
      __builtin_amdgcn_s_setprio(1);
      MFMA16(a00, a01, a10, a11, 6, 7);
      __builtin_amdgcn_s_setprio(0);
      __builtin_amdgcn_sched_barrier(0);
      if (t < NKT - 2)       asm volatile("s_waitcnt vmcnt(4)" ::: "memory");
      else if (t == NKT - 2) asm volatile("s_waitcnt vmcnt(0)" ::: "memory");
      __builtin_amdgcn_sched_barrier(0);
      __builtin_amdgcn_s_barrier();
    }
#undef MFMA16
  }

  // -------- epilogue: distances + per-row (m,s,idx); 2-round LDS scan ------
  // entries per row: 64 (4 wc x 16 lA), each = min/secmin over its 4 j cols.
  // round r covers wc in {2r, 2r+1}: ms [256][32] f32x2 (64KB) + cl u16 (16KB).
  float wnv[4];
#pragma unroll
  for (int n = 0; n < 4; ++n) wnv[n] = wn2[col0 + wc * 64 + n * 16 + lA];

  float gm = FLT_MAX, gs = FLT_MAX; int gc = 0x7fff;
  __syncthreads();
#pragma unroll
  for (int rnd = 0; rnd < 2; ++rnd) {
    if (((wv >> 1) & 1) == rnd) {
      const int e   = ((wc & 1) << 4) + lA;
      char* msW = smem + ((((e >> 1) ^ 0) << 4));  // base; row-xor applied below
#pragma unroll
      for (int i = 0; i < 8; ++i) {
#pragma unroll
        for (int qq = 0; qq < 4; ++qq) {
          const int row = wr * 128 + i * 16 + ((l >> 4) << 2) + qq;
          float m = FLT_MAX, s = FLT_MAX; int c = 0;
#pragma unroll
          for (int j = 0; j < 4; ++j) {
            float d = fmaf(-2.0f, acc[i][j][qq], wnv[j]);
            if (d < m) { s = m; m = d; c = wc * 64 + j * 16 + lA; }
            else if (d < s) s = d;
          }
          *(float2*)(smem + row * 256 + ((((e >> 1) ^ (row & 15)) << 4)) + ((e & 1) << 3)) =
              make_float2(m, s);
          *(ushort*)(smem + 65536 + row * 64 + ((((e >> 3) ^ (row & 3)) << 4)) + ((e & 7) << 1)) =
              (ushort)c;
        }
      }
      (void)msW;
    }
    __syncthreads();
    if (tid < 256) {
      const int row = tid;
#pragma unroll
      for (int h = 0; h < 4; ++h) {
        u16x8 c8 = *(const u16x8*)(smem + 65536 + row * 64 + (((h ^ (row & 3)) << 4)));
#pragma unroll
        for (int g4 = 0; g4 < 4; ++g4) {
          const int g = h * 4 + g4;
          f32x4 v = *(const f32x4*)(smem + row * 256 + (((g ^ (row & 15)) << 4)));
          {
            float me = v[0], se = v[1]; int ce = (int)c8[2 * g4];
            float nm = fminf(gm, me);
            float ns = fminf(fminf(gs, se), fmaxf(gm, me));
            if (me < gm || (me == gm && ce < gc)) gc = ce;
            gm = nm; gs = ns;
          }
          {
            float me = v[2], se = v[3]; int ce = (int)c8[2 * g4 + 1];
            float nm = fminf(gm, me);
            float ns = fminf(fminf(gs, se), fmaxf(gm, me));
            if (me < gm || (me == gm && ce < gc)) gc = ce;
            gm = nm; gs = ns;
          }
        }
      }
    }
    __syncthreads();
  }
  if (tid < 256) {
    size_t o = (size_t)ct * BT_ + row0 + tid;
    tm[o] = gm; ts[o] = gs; ti[o] = col0 + gc;
  }
}

// ---------------- kernel 4: combine tiles per row, flag ambiguous ----------------
__global__ __launch_bounds__(256) void k_combine(const float* __restrict__ tm,
                                                 const float* __restrict__ ts,
                                                 const int* __restrict__ ti,
                                                 int* __restrict__ idxf,
                                                 int* __restrict__ flagged,
                                                 int* __restrict__ count) {
  const int row = blockIdx.x * 256 + threadIdx.x;
  float m = FLT_MAX, s = FLT_MAX; int bi = 0x7fffffff;
  for (int t = 0; t < NTILES; ++t) {
    size_t o = (size_t)t * BT_ + row;
    float om = tm[o], os = ts[o]; int oi = ti[o];
    float nsv = fminf(fminf(s, os), fmaxf(m, om));
    if (om < m || (om == m && oi < bi)) { m = om; bi = oi; }
    s = nsv;
  }
  idxf[row] = bi;
  if (s - m <= THR_) {
    int p = atomicAdd(count, 1);
    flagged[p] = row;
  }
}

// ---------------- kernel 5: exact fp32 refinement of flagged rows ----------------
__global__ __launch_bounds__(128) void k_refine(const float* __restrict__ zn,
                                                const float* __restrict__ w,
                                                const float* __restrict__ wn2,
                                                const float* __restrict__ tm,
                                                const int* __restrict__ flagged,
                                                const int* __restrict__ count,
                                                int* __restrict__ idxf) {
  __shared__ float4 znr[64];
  __shared__ float tmr[32];
  __shared__ float m1s;
  __shared__ float wd[2];
  __shared__ int   wi[2];
  const int tid = threadIdx.x;
  const int cnt = *count;
  for (int f = blockIdx.x; f < cnt; f += gridDim.x) {
    __syncthreads();   // protect LDS reuse across iterations
    const int row = flagged[f];
    if (tid < 64) {
      znr[tid] = *(reinterpret_cast<const float4*>(zn) + (size_t)row * 64 + tid);
    }
    if (tid < 32) {
      float tv = tm[(size_t)tid * BT_ + row];
      tmr[tid] = tv;
      float mm = tv;
#pragma unroll
      for (int msk = 16; msk > 0; msk >>= 1) mm = fminf(mm, __shfl_xor(mm, msk, 64));
      if (tid == 0) m1s = mm;
    }
    __syncthreads();
    const float lim = m1s + THR_;
    float bd = FLT_MAX; int bi = 0x7fffffff;
    for (int t = 0; t < NTILES; ++t) {
      if (tmr[t] <= lim) {
#pragma unroll
        for (int h = 0; h < 2; ++h) {
          int c = t * BN + h * 128 + tid;
          const float4* wr4 = reinterpret_cast<const float4*>(w) + (size_t)c * 64;
          float d0 = 0.f, d1 = 0.f, d2 = 0.f, d3 = 0.f;
#pragma unroll
          for (int k4 = 0; k4 < 16; ++k4) {
            float4 a0 = znr[k4 * 4 + 0], b0 = wr4[k4 * 4 + 0];
            float4 a1 = znr[k4 * 4 + 1], b1 = wr4[k4 * 4 + 1];
            float4 a2 = znr[k4 * 4 + 2], b2 = wr4[k4 * 4 + 2];
            float4 a3 = znr[k4 * 4 + 3], b3 = wr4[k4 * 4 + 3];
            d0 = fmaf(a0.x, b0.x, d0); d0 = fmaf(a0.y, b0.y, d0);
            d0 = fmaf(a0.z, b0.z, d0); d0 = fmaf(a0.w, b0.w, d0);
            d1 = fmaf(a1.x, b1.x, d1); d1 = fmaf(a1.y, b1.y, d1);
            d1 = fmaf(a1.z, b1.z, d1); d1 = fmaf(a1.w, b1.w, d1);
            d2 = fmaf(a2.x, b2.x, d2); d2 = fmaf(a2.y, b2.y, d2);
            d2 = fmaf(a2.z, b2.z, d2); d2 = fmaf(a2.w, b2.w, d2);
            d3 = fmaf(a3.x, b3.x, d3); d3 = fmaf(a3.y, b3.y, d3);
            d3 = fmaf(a3.z, b3.z, d3); d3 = fmaf(a3.w, b3.w, d3);
          }
          float dot = (d0 + d1) + (d2 + d3);
          float d = fmaf(-2.0f, dot, wn2[c]);
          if (d < bd || (d == bd && c < bi)) { bd = d; bi = c; }
        }
      }
    }
#pragma unroll
    for (int msk = 1; msk < 64; msk <<= 1) {
      float od = __shfl_xor(bd, msk, 64);
      int   oi = __shfl_xor(bi, msk, 64);
      if (od < bd || (od == bd && oi < bi)) { bd = od; bi = oi; }
    }
    if ((tid & 63) == 0) { wd[tid >> 6] = bd; wi[tid >> 6] = bi; }
    __syncthreads();
    if (tid == 0) {
      float fd = wd[0]; int fi = wi[0];
      if (wd[1] < fd || (wd[1] == fd && wi[1] < fi)) { fd = wd[1]; fi = wi[1]; }
      idxf[row] = fi;
    }
  }
}

// ---------------- kernel 6: gather + loss partials (atomic-free) ----------------
__global__ __launch_bounds__(256) void k_gather(const float* __restrict__ zn,
                                                const float* __restrict__ w,
                                                const int* __restrict__ idxf,
                                                float* __restrict__ zq,
                                                float* __restrict__ idx_out,
                                                float* __restrict__ wpart) {
  const int row  = blockIdx.x * 4 + (threadIdx.x >> 6);
  const int lane = threadIdx.x & 63;
  const int bi = idxf[row];
  float4 cv = *(reinterpret_cast<const float4*>(w)  + (size_t)bi  * 64 + lane);
  float4 zv = *(reinterpret_cast<const float4*>(zn) + (size_t)row * 64 + lane);
  *(reinterpret_cast<float4*>(zq) + (size_t)row * 64 + lane) = cv;
  float dx = cv.x - zv.x, dy = cv.y - zv.y, dz = cv.z - zv.z, dw = cv.w - zv.w;
  float s = dx * dx + dy * dy + dz * dz + dw * dw;
#pragma unroll
  for (int o = 32; o > 0; o >>= 1) s += __shfl_xor(s, o, 64);
  if (lane == 0) {
    wpart[row] = s;
    idx_out[row] = (float)bi;
  }
}

// ---------------- kernel 7: final loss reduction ----------------
__global__ __launch_bounds__(256) void k_final(const float* __restrict__ wpart,
                                               float* __restrict__ loss_out) {
  __shared__ float wsum[4];
  float s = 0.f;
  for (int i = threadIdx.x; i < BT_; i += 256) s += wpart[i];
#pragma unroll
  for (int o = 32; o > 0; o >>= 1) s += __shfl_xor(s, o, 64);
  if ((threadIdx.x & 63) == 0) wsum[threadIdx.x >> 6] = s;
  __syncthreads();
  if (threadIdx.x == 0)
    loss_out[0] = BETA_ * ((wsum[0] + wsum[1]) + (wsum[2] + wsum[3])) *
                  (1.0f / (float)(BT_ * D_));
}

extern "C" void kernel_launch(void* const* d_in, const int* in_sizes, int n_in,
                              void* d_out, int out_size, void* d_ws, size_t ws_size,
                              hipStream_t stream) {
  const float* z = (const float*)d_in[0];
  const float* w = (const float*)d_in[1];

  float* out      = (float*)d_out;
  float* zq       = out;
  float* loss_out = out + (size_t)BT_ * D_;
  float* idx_out  = loss_out + 1;

  char* wsb = (char*)d_ws;
  float*  zn      = (float*)(wsb);                         // 16 MB
  ushort* Acat    = (ushort*)(wsb + 16777216);             // 24 MB
  ushort* Bcat    = (ushort*)(wsb + 41943040);             // 12 MB
  float*  tm      = (float*)(wsb + 54525952);              // 2 MB used
  float*  ts      = (float*)(wsb + 58720256);              // 2 MB used (reused as wpart)
  int*    ti      = (int*)(wsb + 62914560);                // 2 MB used
  float*  wn2     = (float*)(wsb + 67108864);              // 32 KB
  int*    idxf    = (int*)(wsb + 67141632);                // 64 KB
  int*    flagged = (int*)(wsb + 67207168);                // 64 KB
  int*    count   = (int*)(wsb + 67272704);
  float*  wpart   = ts;   // ts is dead after k_combine

  hipFuncSetAttribute((const void*)k_coarse,
                      hipFuncAttributeMaxDynamicSharedMemorySize, 131072);

  hipMemsetAsync(count, 0, 4, stream);
  k_prep_z<<<BT_ / 4, 256, 0, stream>>>(z, zn, Acat);
  k_prep_w<<<N_ / 4, 256, 0, stream>>>(w, wn2, Bcat);
  k_coarse<<<(BT_ / BM) * NTILES, 512, 131072, stream>>>(Acat, Bcat, wn2, tm, ts, ti);
  k_combine<<<BT_ / 256, 256, 0, stream>>>(tm, ts, ti, idxf, flagged, count);
  k_refine<<<2048, 128, 0, stream>>>(zn, w, wn2, tm, flagged, count, idxf);
  k_gather<<<BT_ / 4, 256, 0, stream>>>(zn, w, idxf, zq, idx_out, wpart);
  k_final<<<1, 256, 0, stream>>>(wpart, loss_out);
}